// Round 15
// baseline (245.551 us; speedup 1.0000x reference)
//
#include <hip/hip_runtime.h>
#include <hip/hip_bf16.h>

typedef __bf16 bf16;
typedef bf16 bf16x8 __attribute__((ext_vector_type(8)));
typedef bf16 bf16x4 __attribute__((ext_vector_type(4)));
typedef float f32x4 __attribute__((ext_vector_type(4)));

#define MFMA16(a, b, c) __builtin_amdgcn_mfma_f32_16x16x32_bf16(a, b, c, 0, 0, 0)

// async global->LDS, 16B per lane. LDS dest is wave-uniform base + lane*16.
__device__ __forceinline__ void g2l16(const bf16* g, bf16* l) {
  __builtin_amdgcn_global_load_lds(
      (__attribute__((address_space(1))) void*)(void*)g,
      (__attribute__((address_space(3))) void*)l,
      16, 0, 0);
}

// In-block dtype sniff: wave 0 ballots exponent sanity of x[0..63] viewed as
// bf16; fp32 data has only ~half sane. Result broadcast via LDS. flag=1=bf16.
__device__ __forceinline__ int sniff_inblock(const void* x, int tid) {
  __shared__ int sf;
  if (tid < 64) {
    unsigned short v = ((const unsigned short*)x)[tid];
    int e = (v >> 7) & 0xFF;
    int sane = (e == 0) || (e >= 112 && e <= 142);
    unsigned long long m = __ballot(sane);
    if (tid == 0) sf = (__popcll(m) >= 56) ? 1 : 0;
  }
  __syncthreads();
  return sf;
}

__device__ __forceinline__ void conv8(const void* in, bf16* out, long i, int f) {
  if (f) {
    ((bf16x8*)out)[i] = ((const bf16x8*)in)[i];
  } else {
    const float4* p = (const float4*)in;
    float4 a = p[i * 2], b = p[i * 2 + 1];
    bf16x8 v;
    v[0] = (bf16)a.x; v[1] = (bf16)a.y; v[2] = (bf16)a.z; v[3] = (bf16)a.w;
    v[4] = (bf16)b.x; v[5] = (bf16)b.y; v[6] = (bf16)b.z; v[7] = (bf16)b.w;
    ((bf16x8*)out)[i] = v;
  }
}

// Canonicalize TWO tensors to bf16 in one launch; flag computed in-block.
__global__ void convert2_to_bf16(const void* __restrict__ a, bf16* __restrict__ oa,
                                 long na8, const void* __restrict__ b,
                                 bf16* __restrict__ ob, long nb8,
                                 const void* __restrict__ x) {
  const int f = sniff_inblock(x, threadIdx.x);
  long i = (long)blockIdx.x * 256 + threadIdx.x;
  if (i < na8) conv8(a, oa, i, f);
  else if (i - na8 < nb8) conv8(b, ob, i - na8, f);
}

// ---------------------------------------------------------------------------
// QKV GEMM: qkv = x @ qkv_w^T, epilogue splits into:
//   Q-third -> qB[n][e] PRE-SCALED by 1/sqrt(64)*log2(e)
//   K-third -> kP: per 64-key tile, key kk -> half kh=kk>>5, k32=kk&31;
//              slot = kh*32 + t*16 + (k32>>3)*4 + (k32&3), t=(k32>>2)&1;
//              chunk = (d>>3)*64 + slot  (kappa for the key-split S^T->PV map)
//   V-third -> vP: chunk = kh*256 + (k32>>3)*64 + d, offset k32&7 (bf16x4)
//
// r15: TILE 128x64 -> 6 BLOCKS/CU. r13 (counted vmcnt) and r14 (XCD chunk)
// were both ~null: load latency is NOT the limiter - the old grid of 768
// blocks (3/CU, grid-limited; VGPR 84 would allow 6) was. The 128-tile
// structure lives on cross-block wave overlap (m114); r9 proved the move
// on gemm_bt (1->2 blk/CU = -7us). Grid (32,48)=1536 = 6 blk/CU =
// 24 waves/CU. LDS 24KB dbuf (fits 6). B staging = one g2l16 (chunk=tid),
// B-frags + epilogue mirror gemm_bt's 64-wide form; a 64-wide tile never
// straddles a third boundary (1024%64==0) so the Q/K/V split is unchanged.
// Keeps r12's 2-phase dbuf prefetch + r14's XCD chunk (8m x 24n per XCD,
// A 2MB + B 3MB L2-resident; bijective for 1536).
// ---------------------------------------------------------------------------
__global__ __launch_bounds__(256) void gemm_qkv(
    const bf16* __restrict__ A, const bf16* __restrict__ B,
    bf16* __restrict__ qB, bf16* __restrict__ kP, bf16* __restrict__ vP) {
  __shared__ __align__(16) bf16 As[2][128 * 32];
  __shared__ __align__(16) bf16 Bs[2][64 * 32];

  const int tid  = threadIdx.x;
  const int lane = tid & 63;
  const int wave = tid >> 6;
  const int wm   = wave >> 1, wn = wave & 1;
  const int l15  = lane & 15, quad = lane >> 4;

  // XCD-chunked block remap: 1536 blocks, XCD c owns 8m x 24n tiles
  const int bidl = (int)blockIdx.x + (int)blockIdx.y * 32;  // 0..1535
  const int xcd  = bidl & 7;
  const int idx  = bidl >> 3;             // 0..191
  const int mb   = (xcd & 3) * 8 + (idx & 7);     // 0..31
  const int nb   = (xcd >> 2) * 24 + (idx >> 3);  // 0..47
  const long m0 = (long)mb * 128;
  const long n0 = (long)nb * 64;
  const int  K  = 1024;

  const bf16* Ab = A + m0 * K;
  const bf16* Bb = B + n0 * K;
  const int rowA = tid & 127;
  const int dc   = tid >> 7;     // A k-chunk pair selector
  const int rowB = tid & 63;     // B row
  const int kcB  = tid >> 6;     // B k-chunk 0..3

  f32x4 acc[4][2] = {};

  // prologue: tile k0=0 -> buf 0
  g2l16(Ab + (long)rowA * K + dc * 8,       As[0] + tid * 8);
  g2l16(Ab + (long)rowA * K + (dc + 2) * 8, As[0] + (tid + 256) * 8);
  g2l16(Bb + (long)rowB * K + kcB * 8,      Bs[0] + tid * 8);
  __syncthreads();

  int cur = 0;
  for (int k0 = 0; k0 < K; k0 += 32) {
    // prefetch NEXT tile into the other buffer (issued before compute)
    if (k0 + 32 < K) {
      const int nbuf = cur ^ 1;
      const long kn = k0 + 32;
      g2l16(Ab + (long)rowA * K + kn + dc * 8,       As[nbuf] + tid * 8);
      g2l16(Ab + (long)rowA * K + kn + (dc + 2) * 8, As[nbuf] + (tid + 256) * 8);
      g2l16(Bb + (long)rowB * K + kn + kcB * 8,      Bs[nbuf] + tid * 8);
    }

    bf16x8 af[4], bfr[2];
#pragma unroll
    for (int t = 0; t < 4; t++)
      af[t]  = *(const bf16x8*)(As[cur] + (quad * 128 + wm * 64 + t * 16 + l15) * 8);
#pragma unroll
    for (int t = 0; t < 2; t++)
      bfr[t] = *(const bf16x8*)(Bs[cur] + (quad * 64 + wn * 32 + t * 16 + l15) * 8);
#pragma unroll
    for (int tm = 0; tm < 4; tm++)
#pragma unroll
      for (int tn = 0; tn < 2; tn++)
        acc[tm][tn] = MFMA16(af[tm], bfr[tn], acc[tm][tn]);

    __syncthreads();  // drains prefetch + all waves' ds_reads of buf[cur]
    cur ^= 1;
  }

  const long rb = m0 + wm * 64;
  const long cb = n0 + wn * 32;
  const int third = (int)(n0 >> 10);
  const float QSC = 0.125f * 1.44269504088896f;

#pragma unroll
  for (int tm = 0; tm < 4; tm++) {
#pragma unroll
    for (int tn = 0; tn < 2; tn++) {
      const long r0 = rb + tm * 16 + quad * 4;
      const long c  = cb + tn * 16 + l15;
      if (third == 0) {
#pragma unroll
        for (int r = 0; r < 4; r++)
          qB[(r0 + r) * 1024 + c] = (bf16)(acc[tm][tn][r] * QSC);
      } else if (third == 1) {
        const int ep = (int)c - 1024;
        const int h = ep >> 6, d = ep & 63;
        const int n0r = (int)r0;
        const int kt = n0r >> 6;
        const int kh = (n0r >> 5) & 1;
        const int t_ = (n0r >> 2) & 1;
        const int mq = (n0r >> 3) & 3;
        const long base = ((long)h * 64 + kt) * 4096 +
                          (((d >> 3) * 64) + kh * 32 + t_ * 16 + mq * 4) * 8 +
                          (d & 7);
#pragma unroll
        for (int r = 0; r < 4; r++)
          kP[base + r * 8] = (bf16)acc[tm][tn][r];
      } else {
        const int ep = (int)c - 2048;
        const int h = ep >> 6, d = ep & 63;
        const int n0r = (int)r0;  // k32&7 = (quad&1)*4 + r
        const int kt = n0r >> 6;
        const int kh = (n0r >> 5) & 1;
        const int kq = (n0r >> 3) & 3;
        bf16x4 v;
#pragma unroll
        for (int r = 0; r < 4; r++) v[r] = (bf16)acc[tm][tn][r];
        *(bf16x4*)(vP + ((long)h * 64 + kt) * 4096 +
                   (kh * 256 + kq * 64 + d) * 8 + (quad & 1) * 4) = v;
      }
    }
  }
}

// ---------------------------------------------------------------------------
// Generic C = A B^T + bias for the out-projection (DYNOUT: runtime out dtype,
// flag computed in-block from x).
// r9: tile 128x64, grid (32,16)=512 = 2 blocks/CU (verified -7us total).
// r12 loop (2-phase dbuf). r14: XCD-chunked grid (8m x 8n per XCD,
// 3MB L2-resident; bijective for 512).
// ---------------------------------------------------------------------------
template <bool BIAS, bool DYNOUT>
__global__ __launch_bounds__(256) void gemm_bt(
    const bf16* __restrict__ A, const bf16* __restrict__ B,
    void* __restrict__ Cv, const bf16* __restrict__ bias,
    int M, int Nn, int K, const void* __restrict__ xs) {
  __shared__ __align__(16) bf16 As[2][128 * 32];
  __shared__ __align__(16) bf16 Bs[2][64 * 32];

  const int tid  = threadIdx.x;
  const int obf = DYNOUT ? sniff_inblock(xs, tid) : 1;

  const int lane = tid & 63;
  const int wave = tid >> 6;
  const int wm   = wave >> 1, wn = wave & 1;
  const int l15  = lane & 15, quad = lane >> 4;

  const int bidl = (int)blockIdx.x + (int)blockIdx.y * 32;  // 0..511
  const int xcd  = bidl & 7;
  const int idx  = bidl >> 3;           // 0..63
  const int mb   = (xcd & 3) * 8 + (idx & 7);   // 0..31
  const int nb   = (xcd >> 2) * 8 + (idx >> 3); // 0..15
  const long m0 = (long)mb * 128;
  const long n0 = (long)nb * 64;

  const bf16* Ab = A + m0 * K;
  const bf16* Bb = B + n0 * K;
  const int rowA = tid & 127;
  const int dc   = tid >> 7;     // A k-chunk pair selector
  const int rowB = tid & 63;     // B row
  const int kcB  = tid >> 6;     // B k-chunk 0..3

  f32x4 acc[4][2] = {};

  // prologue: tile k0=0 -> buf 0
  g2l16(Ab + (long)rowA * K + dc * 8,       As[0] + tid * 8);
  g2l16(Ab + (long)rowA * K + (dc + 2) * 8, As[0] + (tid + 256) * 8);
  g2l16(Bb + (long)rowB * K + kcB * 8,      Bs[0] + tid * 8);
  __syncthreads();

  int cur = 0;
  for (int k0 = 0; k0 < K; k0 += 32) {
    if (k0 + 32 < K) {
      const int nbuf = cur ^ 1;
      const long kn = k0 + 32;
      g2l16(Ab + (long)rowA * K + kn + dc * 8,       As[nbuf] + tid * 8);
      g2l16(Ab + (long)rowA * K + kn + (dc + 2) * 8, As[nbuf] + (tid + 256) * 8);
      g2l16(Bb + (long)rowB * K + kn + kcB * 8,      Bs[nbuf] + tid * 8);
    }

    bf16x8 af[4], bfr[2];
#pragma unroll
    for (int t = 0; t < 4; t++)
      af[t]  = *(const bf16x8*)(As[cur] + (quad * 128 + wm * 64 + t * 16 + l15) * 8);
#pragma unroll
    for (int t = 0; t < 2; t++)
      bfr[t] = *(const bf16x8*)(Bs[cur] + (quad * 64 + wn * 32 + t * 16 + l15) * 8);
#pragma unroll
    for (int tm = 0; tm < 4; tm++)
#pragma unroll
      for (int tn = 0; tn < 2; tn++)
        acc[tm][tn] = MFMA16(af[tm], bfr[tn], acc[tm][tn]);

    __syncthreads();
    cur ^= 1;
  }

  const long rb = m0 + wm * 64;
  const long cb = n0 + wn * 32;
#pragma unroll
  for (int tm = 0; tm < 4; tm++) {
#pragma unroll
    for (int tn = 0; tn < 2; tn++) {
      const long r0 = rb + tm * 16 + quad * 4;
      const long c  = cb + tn * 16 + l15;
      const float bv = BIAS ? (float)bias[c] : 0.0f;
#pragma unroll
      for (int r = 0; r < 4; r++) {
        const float val = acc[tm][tn][r] + bv;
        const long idx2 = (r0 + r) * Nn + c;
        if (DYNOUT && !obf) ((float*)Cv)[idx2] = val;
        else                ((bf16*)Cv)[idx2]  = (bf16)val;
      }
    }
  }
}

// ---------------------------------------------------------------------------
// Flash attention, ALL-REGISTER key-split (r5 structure - the proven best:
// 66.2us; FROZEN). Block = 128 thr = 2 waves (kh = key-half), g=4
// q-subgroups (64 q-rows/block), grid 1024. Every byte of K/V is consumed
// by exactly ONE lane: K/V frags load global->VGPR directly, double-
// buffered in regs. NO __syncthreads in the main loop. setprio(1) on MFMA
// clusters (T5; removing cost 13% in r3).
//
// SESSION LEDGER (flash frozen at its serial-issue ceiling):
//  r2 all-reg 68.8 | r3 no-setprio 77.6 | r4 2048blk 83 | r5 +stagger 66.2
//  r6 skew 69.4 | r7 4w/SIMD spill 696 | r8 kh-stagger 66.5 (null)
// Model: wall/tile/SIMD = MFMA(1400cy) + VALU(1100cy) ~= measured 2580
// across five structures -> same-SIMD serial-issue ceiling; r5 ~97%.
// GEMM ledger: r9 bt 128x64 2blk/CU -7us | r10 BK=64 +7.7us (exposed zero
// overlap: qkv 70.5us MfmaUtil 14%) | r12 2-phase dbuf -11us | r13 counted
// vmcnt null | r14 XCD chunk ~null (latency ruled out) | r15 qkv 6blk/CU.
// ---------------------------------------------------------------------------
__device__ __forceinline__ void attn_tile(
    int kt, const bf16* kb, const bf16* vb, int quad, int koff, int voff,
    const bf16x8 (&qf)[4][2], const bf16x8 (&kcur)[2][2], bf16x8 (&knxt)[2][2],
    const bf16x8& onesf, f32x4 (&oa)[4][4], f32x4 (&la)[4]) {
  // V(t) frags issued early: latency hidden under S MFMAs + exp2
  bf16x8 vf[4];
  const bf16* vt = vb + (long)kt * 4096;
#pragma unroll
  for (int dt = 0; dt < 4; dt++)
    vf[dt] = *(const bf16x8*)(vt + dt * 128 + voff);

  // S^T: this wave's 32 keys (2 tiles of 16) x 64 q (4 subgroups)
  f32x4 s[4][2];
#pragma unroll
  for (int t = 0; t < 2; t++) {
    __builtin_amdgcn_s_setprio(1);
#pragma unroll
    for (int g = 0; g < 4; g++) {
      f32x4 z = {};
      z = MFMA16(kcur[t][0], qf[g][0], z);
      z = MFMA16(kcur[t][1], qf[g][1], z);
      s[g][t] = z;
    }
    __builtin_amdgcn_s_setprio(0);
  }

  // K(t+1) prefetch into the other register set (used next tile)
  const bf16* kn = kb + (long)(kt + 1) * 4096;
#pragma unroll
  for (int t = 0; t < 2; t++)
#pragma unroll
    for (int j = 0; j < 2; j++)
      knxt[t][j] = *(const bf16x8*)(kn + (j * 4 + quad) * 512 + t * 128 + koff);

  // P = exp2(S); pack into PV B-frags: j = t*4 + r (kappa, 32-key form)
  bf16x8 pf[4];
#pragma unroll
  for (int g = 0; g < 4; g++) {
    union { bf16x8 v; __hip_bfloat162 h2[4]; } u;
#pragma unroll
    for (int idx = 0; idx < 4; idx++) {
      const int t = idx >> 1, rr = (idx & 1) * 2;
      float p0 = __builtin_amdgcn_exp2f(s[g][t][rr]);
      float p1 = __builtin_amdgcn_exp2f(s[g][t][rr + 1]);
      u.h2[idx] = __float22bfloat162_rn(float2{p0, p1});
    }
    pf[g] = u.v;
  }

  // O^T += V^T P^T (rank-32 over this wave's keys); l via ones-MFMA
#pragma unroll
  for (int dt = 0; dt < 4; dt++) {
    __builtin_amdgcn_s_setprio(1);
#pragma unroll
    for (int g = 0; g < 4; g++) oa[g][dt] = MFMA16(vf[dt], pf[g], oa[g][dt]);
    __builtin_amdgcn_s_setprio(0);
  }
  __builtin_amdgcn_s_setprio(1);
#pragma unroll
  for (int g = 0; g < 4; g++) la[g] = MFMA16(onesf, pf[g], la[g]);
  __builtin_amdgcn_s_setprio(0);
}

__global__ __launch_bounds__(128, 2) void flash_attn(
    const bf16* __restrict__ qB, const bf16* __restrict__ kP,
    const bf16* __restrict__ vP, bf16* __restrict__ O) {
  __shared__ __align__(16) float red[4096];
  __shared__ float lred[256];

  const int tid = threadIdx.x;   // 0..127
  const int lane = tid & 63;
  const int kh = tid >> 6;       // wave = key-half
  const int l15 = lane & 15, quad = lane >> 4;
  const int bid = blockIdx.x;    // 0..1023
  const int xcd = bid & 7, bi = bid >> 3;
  const int h  = xcd + 8 * (bi >> 6);   // 64 blocks/head, same XCD
  const int qt = bi & 63;
  const int q0 = qt * 64;

  // Phase-stagger: co-resident blocks (breadth-first: bid +-256 apart on a
  // CU) get 0/640/1280/1920-cycle one-time sleeps (r5 exact).
  {
    const int slot = (bid >> 8) & 3;
    if (slot == 1)      __builtin_amdgcn_s_sleep(10);
    else if (slot == 2) __builtin_amdgcn_s_sleep(20);
    else if (slot == 3) __builtin_amdgcn_s_sleep(30);
  }

  // Q^T B-frags for this block's 4 subgroups of 16 (Q pre-scaled)
  bf16x8 qf[4][2];
#pragma unroll
  for (int g = 0; g < 4; g++) {
    const bf16* qrow = qB + (long)(q0 + g * 16 + l15) * 1024 + h * 64;
    qf[g][0] = *(const bf16x8*)(qrow + quad * 8);
    qf[g][1] = *(const bf16x8*)(qrow + 32 + quad * 8);
  }

  bf16x8 onesf;
#pragma unroll
  for (int j = 0; j < 8; j++) onesf[j] = (bf16)1.0f;

  f32x4 oa[4][4] = {};  // [g][dt] partial O^T over this wave's key half
  f32x4 la[4] = {};     // [g] partial l

  const bf16* kb = kP + (long)h * 64 * 4096;
  const bf16* vb = vP + (long)h * 64 * 4096;

  // per-lane element offsets into each 4096-elem tile
  const int koff = (kh * 32 + l15) * 8;               // + (j*4+quad)*512 + t*128
  const int voff = (kh * 256 + quad * 64 + l15) * 8;  // + dt*128

  // prologue: K(0) frags
  bf16x8 kA[2][2], kB[2][2];
#pragma unroll
  for (int t = 0; t < 2; t++)
#pragma unroll
    for (int j = 0; j < 2; j++)
      kA[t][j] = *(const bf16x8*)(kb + (j * 4 + quad) * 512 + t * 128 + koff);

#pragma unroll 1
  for (int kt = 0; kt < 64; kt += 2) {
    attn_tile(kt,     kb, vb, quad, koff, voff, qf, kA, kB, onesf, oa, la);
    attn_tile(kt + 1, kb, vb, quad, koff, voff, qf, kB, kA, onesf, oa, la);
  }

  // --- key-half reduction: kh=1 publishes, kh=0 adds + stores ---
  if (kh == 1) {
#pragma unroll
    for (int g = 0; g < 4; g++)
#pragma unroll
      for (int dt = 0; dt < 4; dt++)
        *(f32x4*)(red + (g * 4 + dt) * 256 + lane * 4) = oa[g][dt];
#pragma unroll
    for (int g = 0; g < 4; g++) lred[g * 64 + lane] = la[g][0];
  }
  __syncthreads();
  if (kh == 0) {
#pragma unroll
    for (int g = 0; g < 4; g++) {
#pragma unroll
      for (int dt = 0; dt < 4; dt++)
        oa[g][dt] += *(const f32x4*)(red + (g * 4 + dt) * 256 + lane * 4);
      const float l = la[g][0] + lred[g * 64 + lane];
      const float inv = 1.0f / l;
      bf16* orow = O + (long)(q0 + g * 16 + l15) * 1024 + h * 64;
#pragma unroll
      for (int dt = 0; dt < 4; dt++) {
        bf16x4 v;
#pragma unroll
        for (int r = 0; r < 4; r++) v[r] = (bf16)(oa[g][dt][r] * inv);
        *(bf16x4*)(orow + dt * 16 + quad * 4) = v;
      }
    }
  }
}

extern "C" void kernel_launch(void* const* d_in, const int* in_sizes, int n_in,
                              void* d_out, int out_size, void* d_ws, size_t ws_size,
                              hipStream_t stream) {
  const void* x     = d_in[0];  // [4096][1024]  fp32 or bf16
  const void* qkv_w = d_in[1];  // [3072][1024]
  const void* out_w = d_in[2];  // [1024][1024]
  const void* out_b = d_in[3];  // [1024]

  char* ws = (char*)d_ws;
  bf16* qB   = (bf16*)(ws);                     // 8 MB  [gemm1 -> flash]
  bf16* kP   = (bf16*)(ws + 8388608);           // 8 MB  [gemm1 -> flash]
  bf16* vP   = (bf16*)(ws + 16777216);          // 8 MB  [gemm1 -> flash]
  bf16* ob   = (bf16*)(ws + 25165824);          // 8 MB  [flash -> gemm2]
  bf16* qwb  = (bf16*)(ws + 33554432);          // 6 MB  [conv -> gemm1]
  bf16* xb   = ob;                              // x bf16 (dead before flash)
  bf16* owb  = qB;                              // out_w bf16 (qB dead after flash)
  bf16* obb  = qB + 1048576;                    // out_b bf16

  convert2_to_bf16<<<3584, 256, 0, stream>>>(x, xb, 524288, qkv_w, qwb, 393216, x);

  gemm_qkv<<<dim3(32, 48), 256, 0, stream>>>(xb, qwb, qB, kP, vP);

  flash_attn<<<1024, 128, 0, stream>>>(qB, kP, vP, ob);

  convert2_to_bf16<<<513, 256, 0, stream>>>(out_w, owb, 131072, out_b, obb, 128, x);

  gemm_bt<true, true><<<dim3(32, 16), 256, 0, stream>>>(
      ob, owb, d_out, obb, 4096, 1024, 1024, x);
}

// Round 17
// 224.112 us; speedup vs baseline: 1.0957x; 1.0957x over previous
//
#include <hip/hip_runtime.h>
#include <hip/hip_bf16.h>

typedef __bf16 bf16;
typedef bf16 bf16x8 __attribute__((ext_vector_type(8)));
typedef bf16 bf16x4 __attribute__((ext_vector_type(4)));
typedef float f32x4 __attribute__((ext_vector_type(4)));

#define MFMA16(a, b, c) __builtin_amdgcn_mfma_f32_16x16x32_bf16(a, b, c, 0, 0, 0)

// async global->LDS, 16B per lane. LDS dest is wave-uniform base + lane*16.
__device__ __forceinline__ void g2l16(const bf16* g, bf16* l) {
  __builtin_amdgcn_global_load_lds(
      (__attribute__((address_space(1))) void*)(void*)g,
      (__attribute__((address_space(3))) void*)l,
      16, 0, 0);
}

// In-block dtype sniff: wave 0 ballots exponent sanity of x[0..63] viewed as
// bf16; fp32 data has only ~half sane. Result broadcast via LDS. flag=1=bf16.
__device__ __forceinline__ int sniff_inblock(const void* x, int tid) {
  __shared__ int sf;
  if (tid < 64) {
    unsigned short v = ((const unsigned short*)x)[tid];
    int e = (v >> 7) & 0xFF;
    int sane = (e == 0) || (e >= 112 && e <= 142);
    unsigned long long m = __ballot(sane);
    if (tid == 0) sf = (__popcll(m) >= 56) ? 1 : 0;
  }
  __syncthreads();
  return sf;
}

__device__ __forceinline__ void conv8(const void* in, bf16* out, long i, int f) {
  if (f) {
    ((bf16x8*)out)[i] = ((const bf16x8*)in)[i];
  } else {
    const float4* p = (const float4*)in;
    float4 a = p[i * 2], b = p[i * 2 + 1];
    bf16x8 v;
    v[0] = (bf16)a.x; v[1] = (bf16)a.y; v[2] = (bf16)a.z; v[3] = (bf16)a.w;
    v[4] = (bf16)b.x; v[5] = (bf16)b.y; v[6] = (bf16)b.z; v[7] = (bf16)b.w;
    ((bf16x8*)out)[i] = v;
  }
}

// Canonicalize TWO tensors to bf16 in one launch; flag computed in-block.
__global__ void convert2_to_bf16(const void* __restrict__ a, bf16* __restrict__ oa,
                                 long na8, const void* __restrict__ b,
                                 bf16* __restrict__ ob, long nb8,
                                 const void* __restrict__ x) {
  const int f = sniff_inblock(x, threadIdx.x);
  long i = (long)blockIdx.x * 256 + threadIdx.x;
  if (i < na8) conv8(a, oa, i, f);
  else if (i - na8 < nb8) conv8(b, ob, i - na8, f);
}

// ---------------------------------------------------------------------------
// QKV GEMM: qkv = x @ qkv_w^T, epilogue splits into:
//   Q-third -> qB[n][e] PRE-SCALED by 1/sqrt(64)*log2(e)
//   K-third -> kP: per 64-key tile, key kk -> half kh=kk>>5, k32=kk&31;
//              slot = kh*32 + t*16 + (k32>>3)*4 + (k32&3), t=(k32>>2)&1;
//              chunk = (d>>3)*64 + slot  (kappa for the key-split S^T->PV map)
//   V-third -> vP: chunk = kh*256 + (k32>>3)*64 + d, offset k32&7 (bf16x4)
//
// r17 = r14 exact (the verified best, 224.8us; r16's failure was a launch
// typo: gemm_bt grid (32,8) under the 512-block XCD remap left half the
// output columns unwritten - kernels were correct, the grid wasn't).
// GEMM family ledger: r10 BK=64 +7.7 | r12 2-phase dbuf -11 | r13 counted
// vmcnt null | r14 XCD chunk ~null | r15 128x64 6blk/CU -21 (intensity
// halved -> staging-throughput-bound). ~470 TF is this family's plateau
// at K=1024.
// ---------------------------------------------------------------------------
__global__ __launch_bounds__(256) void gemm_qkv(
    const bf16* __restrict__ A, const bf16* __restrict__ B,
    bf16* __restrict__ qB, bf16* __restrict__ kP, bf16* __restrict__ vP) {
  __shared__ __align__(16) bf16 As[2][128 * 32];
  __shared__ __align__(16) bf16 Bs[2][128 * 32];

  const int tid  = threadIdx.x;
  const int lane = tid & 63;
  const int wave = tid >> 6;
  const int wm   = wave >> 1, wn = wave & 1;
  const int l15  = lane & 15, quad = lane >> 4;

  // XCD-chunked block remap (bijective for 768 blocks; 8m x 12n per XCD)
  const int bidl = (int)blockIdx.x + (int)blockIdx.y * 32;  // 0..767
  const int xcd  = bidl & 7;
  const int idx  = bidl >> 3;            // 0..95
  const int mb   = (xcd & 3) * 8 + (idx & 7);    // 0..31
  const int nb   = (xcd >> 2) * 12 + (idx >> 3); // 0..23
  const long m0 = (long)mb * 128;
  const long n0 = (long)nb * 128;
  const int  K  = 1024;

  const bf16* Ab = A + m0 * K;
  const bf16* Bb = B + n0 * K;
  const int rowA = tid & 127;
  const int dc   = tid >> 7;

  f32x4 acc[4][4] = {};

  // prologue: tile k0=0 -> buf 0
  g2l16(Ab + (long)rowA * K + dc * 8,       As[0] + tid * 8);
  g2l16(Ab + (long)rowA * K + (dc + 2) * 8, As[0] + (tid + 256) * 8);
  g2l16(Bb + (long)rowA * K + dc * 8,       Bs[0] + tid * 8);
  g2l16(Bb + (long)rowA * K + (dc + 2) * 8, Bs[0] + (tid + 256) * 8);
  __syncthreads();

  int cur = 0;
  for (int k0 = 0; k0 < K; k0 += 32) {
    // prefetch NEXT tile into the other buffer (issued before compute;
    // latency hides under the ds_read+MFMA phase below)
    if (k0 + 32 < K) {
      const int nbuf = cur ^ 1;
      const long kn = k0 + 32;
      g2l16(Ab + (long)rowA * K + kn + dc * 8,       As[nbuf] + tid * 8);
      g2l16(Ab + (long)rowA * K + kn + (dc + 2) * 8, As[nbuf] + (tid + 256) * 8);
      g2l16(Bb + (long)rowA * K + kn + dc * 8,       Bs[nbuf] + tid * 8);
      g2l16(Bb + (long)rowA * K + kn + (dc + 2) * 8, Bs[nbuf] + (tid + 256) * 8);
    }

    bf16x8 af[4], bfr[4];
#pragma unroll
    for (int t = 0; t < 4; t++) {
      af[t]  = *(const bf16x8*)(As[cur] + (quad * 128 + wm * 64 + t * 16 + l15) * 8);
      bfr[t] = *(const bf16x8*)(Bs[cur] + (quad * 128 + wn * 64 + t * 16 + l15) * 8);
    }
#pragma unroll
    for (int tm = 0; tm < 4; tm++)
#pragma unroll
      for (int tn = 0; tn < 4; tn++)
        acc[tm][tn] = MFMA16(af[tm], bfr[tn], acc[tm][tn]);

    __syncthreads();  // drains prefetch + all waves' ds_reads of buf[cur]
    cur ^= 1;
  }

  const long rb = m0 + wm * 64;
  const long cb = n0 + wn * 64;
  const int third = (int)(n0 >> 10);
  const float QSC = 0.125f * 1.44269504088896f;

#pragma unroll
  for (int tm = 0; tm < 4; tm++) {
#pragma unroll
    for (int tn = 0; tn < 4; tn++) {
      const long r0 = rb + tm * 16 + quad * 4;
      const long c  = cb + tn * 16 + l15;
      if (third == 0) {
#pragma unroll
        for (int r = 0; r < 4; r++)
          qB[(r0 + r) * 1024 + c] = (bf16)(acc[tm][tn][r] * QSC);
      } else if (third == 1) {
        const int ep = (int)c - 1024;
        const int h = ep >> 6, d = ep & 63;
        const int n0r = (int)r0;
        const int kt = n0r >> 6;
        const int kh = (n0r >> 5) & 1;
        const int t_ = (n0r >> 2) & 1;
        const int mq = (n0r >> 3) & 3;
        const long base = ((long)h * 64 + kt) * 4096 +
                          (((d >> 3) * 64) + kh * 32 + t_ * 16 + mq * 4) * 8 +
                          (d & 7);
#pragma unroll
        for (int r = 0; r < 4; r++)
          kP[base + r * 8] = (bf16)acc[tm][tn][r];
      } else {
        const int ep = (int)c - 2048;
        const int h = ep >> 6, d = ep & 63;
        const int n0r = (int)r0;  // k32&7 = (quad&1)*4 + r
        const int kt = n0r >> 6;
        const int kh = (n0r >> 5) & 1;
        const int kq = (n0r >> 3) & 3;
        bf16x4 v;
#pragma unroll
        for (int r = 0; r < 4; r++) v[r] = (bf16)acc[tm][tn][r];
        *(bf16x4*)(vP + ((long)h * 64 + kt) * 4096 +
                   (kh * 256 + kq * 64 + d) * 8 + (quad & 1) * 4) = v;
      }
    }
  }
}

// ---------------------------------------------------------------------------
// Generic C = A B^T + bias for the out-projection (DYNOUT: runtime out dtype,
// flag computed in-block from x).
// r9: tile 128x64, grid (32,16)=512 = 2 blocks/CU (verified -7us total).
// r12 loop (2-phase dbuf). r14: XCD-chunked grid (8m x 8n per XCD,
// 3MB L2-resident; bijective for 512 blocks -> REQUIRES grid (32,16)).
// ---------------------------------------------------------------------------
template <bool BIAS, bool DYNOUT>
__global__ __launch_bounds__(256) void gemm_bt(
    const bf16* __restrict__ A, const bf16* __restrict__ B,
    void* __restrict__ Cv, const bf16* __restrict__ bias,
    int M, int Nn, int K, const void* __restrict__ xs) {
  __shared__ __align__(16) bf16 As[2][128 * 32];
  __shared__ __align__(16) bf16 Bs[2][64 * 32];

  const int tid  = threadIdx.x;
  const int obf = DYNOUT ? sniff_inblock(xs, tid) : 1;

  const int lane = tid & 63;
  const int wave = tid >> 6;
  const int wm   = wave >> 1, wn = wave & 1;
  const int l15  = lane & 15, quad = lane >> 4;

  const int bidl = (int)blockIdx.x + (int)blockIdx.y * 32;  // 0..511
  const int xcd  = bidl & 7;
  const int idx  = bidl >> 3;           // 0..63
  const int mb   = (xcd & 3) * 8 + (idx & 7);   // 0..31
  const int nb   = (xcd >> 2) * 8 + (idx >> 3); // 0..15
  const long m0 = (long)mb * 128;
  const long n0 = (long)nb * 64;

  const bf16* Ab = A + m0 * K;
  const bf16* Bb = B + n0 * K;
  const int rowA = tid & 127;
  const int dc   = tid >> 7;     // A k-chunk pair selector
  const int rowB = tid & 63;     // B row
  const int kcB  = tid >> 6;     // B k-chunk 0..3

  f32x4 acc[4][2] = {};

  // prologue: tile k0=0 -> buf 0
  g2l16(Ab + (long)rowA * K + dc * 8,       As[0] + tid * 8);
  g2l16(Ab + (long)rowA * K + (dc + 2) * 8, As[0] + (tid + 256) * 8);
  g2l16(Bb + (long)rowB * K + kcB * 8,      Bs[0] + tid * 8);
  __syncthreads();

  int cur = 0;
  for (int k0 = 0; k0 < K; k0 += 32) {
    if (k0 + 32 < K) {
      const int nbuf = cur ^ 1;
      const long kn = k0 + 32;
      g2l16(Ab + (long)rowA * K + kn + dc * 8,       As[nbuf] + tid * 8);
      g2l16(Ab + (long)rowA * K + kn + (dc + 2) * 8, As[nbuf] + (tid + 256) * 8);
      g2l16(Bb + (long)rowB * K + kn + kcB * 8,      Bs[nbuf] + tid * 8);
    }

    bf16x8 af[4], bfr[2];
#pragma unroll
    for (int t = 0; t < 4; t++)
      af[t]  = *(const bf16x8*)(As[cur] + (quad * 128 + wm * 64 + t * 16 + l15) * 8);
#pragma unroll
    for (int t = 0; t < 2; t++)
      bfr[t] = *(const bf16x8*)(Bs[cur] + (quad * 64 + wn * 32 + t * 16 + l15) * 8);
#pragma unroll
    for (int tm = 0; tm < 4; tm++)
#pragma unroll
      for (int tn = 0; tn < 2; tn++)
        acc[tm][tn] = MFMA16(af[tm], bfr[tn], acc[tm][tn]);

    __syncthreads();
    cur ^= 1;
  }

  const long rb = m0 + wm * 64;
  const long cb = n0 + wn * 32;
#pragma unroll
  for (int tm = 0; tm < 4; tm++) {
#pragma unroll
    for (int tn = 0; tn < 2; tn++) {
      const long r0 = rb + tm * 16 + quad * 4;
      const long c  = cb + tn * 16 + l15;
      const float bv = BIAS ? (float)bias[c] : 0.0f;
#pragma unroll
      for (int r = 0; r < 4; r++) {
        const float val = acc[tm][tn][r] + bv;
        const long idx2 = (r0 + r) * Nn + c;
        if (DYNOUT && !obf) ((float*)Cv)[idx2] = val;
        else                ((bf16*)Cv)[idx2]  = (bf16)val;
      }
    }
  }
}

// ---------------------------------------------------------------------------
// Flash attention, ALL-REGISTER key-split (r5 structure - the proven best:
// 66.2us; FROZEN). Block = 128 thr = 2 waves (kh = key-half), g=4
// q-subgroups (64 q-rows/block), grid 1024. Every byte of K/V is consumed
// by exactly ONE lane: K/V frags load global->VGPR directly, double-
// buffered in regs. NO __syncthreads in the main loop. setprio(1) on MFMA
// clusters (T5; removing cost 13% in r3).
//
// SESSION LEDGER (flash frozen at its serial-issue ceiling):
//  r2 all-reg 68.8 | r3 no-setprio 77.6 | r4 2048blk 83 | r5 +stagger 66.2
//  r6 skew 69.4 | r7 4w/SIMD spill 696 | r8 kh-stagger 66.5 (null)
// Model: wall/tile/SIMD = MFMA(1400cy) + VALU(1100cy) ~= measured 2580
// across five structures -> same-SIMD serial-issue ceiling; r5 ~97%.
// GEMM ledger: r9 bt 2blk/CU -7 | r10 BK=64 +7.7 | r12 2-phase -11 |
// r13 counted-vmcnt null | r14 XCD chunk ~null | r15 6blk/CU -21 (reverted)
// | r16 launch-grid typo (failed; fixed here).
// ---------------------------------------------------------------------------
__device__ __forceinline__ void attn_tile(
    int kt, const bf16* kb, const bf16* vb, int quad, int koff, int voff,
    const bf16x8 (&qf)[4][2], const bf16x8 (&kcur)[2][2], bf16x8 (&knxt)[2][2],
    const bf16x8& onesf, f32x4 (&oa)[4][4], f32x4 (&la)[4]) {
  // V(t) frags issued early: latency hidden under S MFMAs + exp2
  bf16x8 vf[4];
  const bf16* vt = vb + (long)kt * 4096;
#pragma unroll
  for (int dt = 0; dt < 4; dt++)
    vf[dt] = *(const bf16x8*)(vt + dt * 128 + voff);

  // S^T: this wave's 32 keys (2 tiles of 16) x 64 q (4 subgroups)
  f32x4 s[4][2];
#pragma unroll
  for (int t = 0; t < 2; t++) {
    __builtin_amdgcn_s_setprio(1);
#pragma unroll
    for (int g = 0; g < 4; g++) {
      f32x4 z = {};
      z = MFMA16(kcur[t][0], qf[g][0], z);
      z = MFMA16(kcur[t][1], qf[g][1], z);
      s[g][t] = z;
    }
    __builtin_amdgcn_s_setprio(0);
  }

  // K(t+1) prefetch into the other register set (used next tile)
  const bf16* kn = kb + (long)(kt + 1) * 4096;
#pragma unroll
  for (int t = 0; t < 2; t++)
#pragma unroll
    for (int j = 0; j < 2; j++)
      knxt[t][j] = *(const bf16x8*)(kn + (j * 4 + quad) * 512 + t * 128 + koff);

  // P = exp2(S); pack into PV B-frags: j = t*4 + r (kappa, 32-key form)
  bf16x8 pf[4];
#pragma unroll
  for (int g = 0; g < 4; g++) {
    union { bf16x8 v; __hip_bfloat162 h2[4]; } u;
#pragma unroll
    for (int idx = 0; idx < 4; idx++) {
      const int t = idx >> 1, rr = (idx & 1) * 2;
      float p0 = __builtin_amdgcn_exp2f(s[g][t][rr]);
      float p1 = __builtin_amdgcn_exp2f(s[g][t][rr + 1]);
      u.h2[idx] = __float22bfloat162_rn(float2{p0, p1});
    }
    pf[g] = u.v;
  }

  // O^T += V^T P^T (rank-32 over this wave's keys); l via ones-MFMA
#pragma unroll
  for (int dt = 0; dt < 4; dt++) {
    __builtin_amdgcn_s_setprio(1);
#pragma unroll
    for (int g = 0; g < 4; g++) oa[g][dt] = MFMA16(vf[dt], pf[g], oa[g][dt]);
    __builtin_amdgcn_s_setprio(0);
  }
  __builtin_amdgcn_s_setprio(1);
#pragma unroll
  for (int g = 0; g < 4; g++) la[g] = MFMA16(onesf, pf[g], la[g]);
  __builtin_amdgcn_s_setprio(0);
}

__global__ __launch_bounds__(128, 2) void flash_attn(
    const bf16* __restrict__ qB, const bf16* __restrict__ kP,
    const bf16* __restrict__ vP, bf16* __restrict__ O) {
  __shared__ __align__(16) float red[4096];
  __shared__ float lred[256];

  const int tid = threadIdx.x;   // 0..127
  const int lane = tid & 63;
  const int kh = tid >> 6;       // wave = key-half
  const int l15 = lane & 15, quad = lane >> 4;
  const int bid = blockIdx.x;    // 0..1023
  const int xcd = bid & 7, bi = bid >> 3;
  const int h  = xcd + 8 * (bi >> 6);   // 64 blocks/head, same XCD
  const int qt = bi & 63;
  const int q0 = qt * 64;

  // Phase-stagger: co-resident blocks (breadth-first: bid +-256 apart on a
  // CU) get 0/640/1280/1920-cycle one-time sleeps (r5 exact).
  {
    const int slot = (bid >> 8) & 3;
    if (slot == 1)      __builtin_amdgcn_s_sleep(10);
    else if (slot == 2) __builtin_amdgcn_s_sleep(20);
    else if (slot == 3) __builtin_amdgcn_s_sleep(30);
  }

  // Q^T B-frags for this block's 4 subgroups of 16 (Q pre-scaled)
  bf16x8 qf[4][2];
#pragma unroll
  for (int g = 0; g < 4; g++) {
    const bf16* qrow = qB + (long)(q0 + g * 16 + l15) * 1024 + h * 64;
    qf[g][0] = *(const bf16x8*)(qrow + quad * 8);
    qf[g][1] = *(const bf16x8*)(qrow + 32 + quad * 8);
  }

  bf16x8 onesf;
#pragma unroll
  for (int j = 0; j < 8; j++) onesf[j] = (bf16)1.0f;

  f32x4 oa[4][4] = {};  // [g][dt] partial O^T over this wave's key half
  f32x4 la[4] = {};     // [g] partial l

  const bf16* kb = kP + (long)h * 64 * 4096;
  const bf16* vb = vP + (long)h * 64 * 4096;

  // per-lane element offsets into each 4096-elem tile
  const int koff = (kh * 32 + l15) * 8;               // + (j*4+quad)*512 + t*128
  const int voff = (kh * 256 + quad * 64 + l15) * 8;  // + dt*128

  // prologue: K(0) frags
  bf16x8 kA[2][2], kB[2][2];
#pragma unroll
  for (int t = 0; t < 2; t++)
#pragma unroll
    for (int j = 0; j < 2; j++)
      kA[t][j] = *(const bf16x8*)(kb + (j * 4 + quad) * 512 + t * 128 + koff);

#pragma unroll 1
  for (int kt = 0; kt < 64; kt += 2) {
    attn_tile(kt,     kb, vb, quad, koff, voff, qf, kA, kB, onesf, oa, la);
    attn_tile(kt + 1, kb, vb, quad, koff, voff, qf, kB, kA, onesf, oa, la);
  }

  // --- key-half reduction: kh=1 publishes, kh=0 adds + stores ---
  if (kh == 1) {
#pragma unroll
    for (int g = 0; g < 4; g++)
#pragma unroll
      for (int dt = 0; dt < 4; dt++)
        *(f32x4*)(red + (g * 4 + dt) * 256 + lane * 4) = oa[g][dt];
#pragma unroll
    for (int g = 0; g < 4; g++) lred[g * 64 + lane] = la[g][0];
  }
  __syncthreads();
  if (kh == 0) {
#pragma unroll
    for (int g = 0; g < 4; g++) {
#pragma unroll
      for (int dt = 0; dt < 4; dt++)
        oa[g][dt] += *(const f32x4*)(red + (g * 4 + dt) * 256 + lane * 4);
      const float l = la[g][0] + lred[g * 64 + lane];
      const float inv = 1.0f / l;
      bf16* orow = O + (long)(q0 + g * 16 + l15) * 1024 + h * 64;
#pragma unroll
      for (int dt = 0; dt < 4; dt++) {
        bf16x4 v;
#pragma unroll
        for (int r = 0; r < 4; r++) v[r] = (bf16)(oa[g][dt][r] * inv);
        *(bf16x4*)(orow + dt * 16 + quad * 4) = v;
      }
    }
  }
}

extern "C" void kernel_launch(void* const* d_in, const int* in_sizes, int n_in,
                              void* d_out, int out_size, void* d_ws, size_t ws_size,
                              hipStream_t stream) {
  const void* x     = d_in[0];  // [4096][1024]  fp32 or bf16
  const void* qkv_w = d_in[1];  // [3072][1024]
  const void* out_w = d_in[2];  // [1024][1024]
  const void* out_b = d_in[3];  // [1024]

  char* ws = (char*)d_ws;
  bf16* qB   = (bf16*)(ws);                     // 8 MB  [gemm1 -> flash]
  bf16* kP   = (bf16*)(ws + 8388608);           // 8 MB  [gemm1 -> flash]
  bf16* vP   = (bf16*)(ws + 16777216);          // 8 MB  [gemm1 -> flash]
  bf16* ob   = (bf16*)(ws + 25165824);          // 8 MB  [flash -> gemm2]
  bf16* qwb  = (bf16*)(ws + 33554432);          // 6 MB  [conv -> gemm1]
  bf16* xb   = ob;                              // x bf16 (dead before flash)
  bf16* owb  = qB;                              // out_w bf16 (qB dead after flash)
  bf16* obb  = qB + 1048576;                    // out_b bf16

  convert2_to_bf16<<<3584, 256, 0, stream>>>(x, xb, 524288, qkv_w, qwb, 393216, x);

  gemm_qkv<<<dim3(32, 24), 256, 0, stream>>>(xb, qwb, qB, kP, vP);

  flash_attn<<<1024, 128, 0, stream>>>(qB, kP, vP, ob);

  convert2_to_bf16<<<513, 256, 0, stream>>>(out_w, owb, 131072, out_b, obb, 128, x);

  gemm_bt<true, true><<<dim3(32, 16), 256, 0, stream>>>(
      ob, owb, d_out, obb, 4096, 1024, 1024, x);
}